// Round 1
// baseline (989.475 us; speedup 1.0000x reference)
//
#include <hip/hip_runtime.h>
#include <stdint.h>

// MoE FFN: B=4 T=1024 C=1024 H=4096 E=8 K=2  (N=4096 tokens, 8192 assignments)
// Sparse top-2 formulation, bf16 MFMA, fp32 accumulate.
// Requires ws_size >= ~94.6 MB.

#define N_TOK 4096
#define C_DIM 1024
#define H_DIM 4096
#define E_NUM 8

#define BM 128
#define BN1 64     // gemm1: h-cols per block (per W1/W3 matrix)
#define BN2 128    // gemm2: c-cols per block
#define BK 64
#define MAXROWS 9216            // 8192 + 8*128 padding headroom
#define MAXTILES (MAXROWS / BM) // 72

typedef float f32x4 __attribute__((ext_vector_type(4)));
typedef short s16x8 __attribute__((ext_vector_type(8)));
typedef unsigned short u16x4 __attribute__((ext_vector_type(4)));
typedef unsigned short ushort_t;

// ---- ws layout (int indices for header/small arrays, byte offsets for big) ----
#define OFF_COUNTS 0                        // int[8]
#define OFF_FILL   8                        // int[8]
#define OFF_PADOFF 16                       // int[9]  (BM-aligned segment starts, [8]=total)
#define OFF_TOKIDX 64                       // int[N*2]
#define OFF_TOKW   (OFF_TOKIDX + N_TOK * 2) // float[N*2]
#define OFF_ATOK   (OFF_TOKW + N_TOK * 2)   // int[MAXROWS] assignment -> token
#define OFF_AW     (OFF_ATOK + MAXROWS)     // float[MAXROWS] assignment gate weight
#define OFF_END    (OFF_AW + MAXROWS)
#define BOFF_PACKA ((OFF_END * 4 + 255) / 256 * 256)      // bf16 [MAXROWS][C]
#define BOFF_HIDDEN (BOFF_PACKA + MAXROWS * C_DIM * 2)    // bf16 [MAXROWS][H]

__device__ __forceinline__ ushort_t f2bf(float f) {
  uint32_t u = __float_as_uint(f);
  u += 0x7FFFu + ((u >> 16) & 1u);   // RNE
  return (ushort_t)(u >> 16);
}

__device__ __forceinline__ void mfma_bf16(f32x4& d, s16x8 a, s16x8 b) {
  // D[i][j] += sum_k A[i][k]*B[k][j]; A: row=l&15,k=8*(l>>4)+j ; B: col=l&15 same k
  asm volatile("v_mfma_f32_16x16x32_bf16 %0, %1, %2, %0" : "+v"(d) : "v"(a), "v"(b));
}

// ---------------- router: logits, top-2, renorm weights, expert counts ----------------
__global__ __launch_bounds__(256) void router_k(const float* __restrict__ x,
                                                const float* __restrict__ Wg,
                                                int* __restrict__ wsI) {
  int lane = threadIdx.x & 63;
  int wave = threadIdx.x >> 6;
  int t = blockIdx.x * 4 + wave;
  const float* xr = x + (size_t)t * C_DIM;
  float acc[E_NUM];
#pragma unroll
  for (int e = 0; e < E_NUM; e++) acc[e] = 0.f;
#pragma unroll
  for (int i = 0; i < C_DIM / 64; i++) {
    int c = i * 64 + lane;
    float xv = xr[c];
    const float4* wr = (const float4*)(Wg + (size_t)c * E_NUM);
    float4 w0 = wr[0], w1 = wr[1];
    acc[0] += xv * w0.x; acc[1] += xv * w0.y;
    acc[2] += xv * w0.z; acc[3] += xv * w0.w;
    acc[4] += xv * w1.x; acc[5] += xv * w1.y;
    acc[6] += xv * w1.z; acc[7] += xv * w1.w;
  }
#pragma unroll
  for (int e = 0; e < E_NUM; e++) {
    float v = acc[e];
#pragma unroll
    for (int off = 32; off > 0; off >>= 1) v += __shfl_down(v, off);
    acc[e] = v;
  }
  if (lane == 0) {
    float m0 = -1e30f, m1 = -1e30f;
    int i0 = 0, i1 = 0;
#pragma unroll
    for (int e = 0; e < E_NUM; e++) {
      float v = acc[e];
      if (v > m0) { m1 = m0; i1 = i0; m0 = v; i0 = e; }
      else if (v > m1) { m1 = v; i1 = e; }
    }
    // renormalized top-2 softmax weights: denominator cancels
    float w0 = 1.f / (1.f + __expf(m1 - m0));
    wsI[OFF_TOKIDX + t * 2] = i0;
    wsI[OFF_TOKIDX + t * 2 + 1] = i1;
    float* tw = (float*)(wsI + OFF_TOKW);
    tw[t * 2] = w0;
    tw[t * 2 + 1] = 1.f - w0;
    atomicAdd(&wsI[OFF_COUNTS + i0], 1);
    atomicAdd(&wsI[OFF_COUNTS + i1], 1);
  }
}

// ---------------- offsets: BM-aligned segment starts + pad-row fill ----------------
__global__ __launch_bounds__(256) void offsets_k(int* __restrict__ wsI) {
  __shared__ int s_off[E_NUM + 1], s_cnt[E_NUM], s_pad[E_NUM];
  if (threadIdx.x == 0) {
    int tot = 0;
    for (int e = 0; e < E_NUM; e++) {
      int c = wsI[OFF_COUNTS + e];
      s_cnt[e] = c;
      s_off[e] = tot;
      int p = (c + BM - 1) / BM * BM;
      s_pad[e] = p;
      tot += p;
      wsI[OFF_PADOFF + e] = s_off[e];
    }
    s_off[E_NUM] = tot;
    wsI[OFF_PADOFF + E_NUM] = tot;
  }
  __syncthreads();
  int* atok = wsI + OFF_ATOK;
  float* aw = (float*)(wsI + OFF_AW);
  for (int e = 0; e < E_NUM; e++) {
    int start = s_off[e] + s_cnt[e];
    int end = s_off[e] + s_pad[e];
    for (int r = start + (int)threadIdx.x; r < end; r += 256) {
      atok[r] = 0;    // pad row: token 0, weight 0 -> contributes nothing
      aw[r] = 0.f;
    }
  }
}

// ---------------- scatter tokens into expert segments ----------------
__global__ __launch_bounds__(256) void scatter_k(int* __restrict__ wsI) {
  int g = blockIdx.x * 256 + threadIdx.x;   // 0..8191 (token*2+k)
  int e = wsI[OFF_TOKIDX + g];
  int pos = wsI[OFF_PADOFF + e] + atomicAdd(&wsI[OFF_FILL + e], 1);
  wsI[OFF_ATOK + pos] = g >> 1;
  ((float*)(wsI + OFF_AW))[pos] = ((const float*)(wsI + OFF_TOKW))[g];
}

// ---------------- pack gathered x rows to bf16 ----------------
__global__ __launch_bounds__(256) void pack_k(const float* __restrict__ x,
                                              const int* __restrict__ wsI,
                                              ushort_t* __restrict__ packA) {
  int row = blockIdx.x * 2 + (threadIdx.x >> 7);
  if (row >= wsI[OFF_PADOFF + E_NUM]) return;
  int t = wsI[OFF_ATOK + row];
  int c = (threadIdx.x & 127) * 8;
  const float4* src = (const float4*)(x + (size_t)t * C_DIM + c);
  float4 a = src[0], b = src[1];
  u16x4 o0 = { f2bf(a.x), f2bf(a.y), f2bf(a.z), f2bf(a.w) };
  u16x4 o1 = { f2bf(b.x), f2bf(b.y), f2bf(b.z), f2bf(b.w) };
  *(u16x4*)(packA + (size_t)row * C_DIM + c) = o0;
  *(u16x4*)(packA + (size_t)row * C_DIM + c + 4) = o1;
}

// ---------------- GEMM1: hidden = silu(A@W1[e]) * (A@W3[e]), bf16 out ----------------
__global__ __launch_bounds__(256, 2) void gemm1_k(const ushort_t* __restrict__ packA,
                                                  const float* __restrict__ W1,
                                                  const float* __restrict__ W3,
                                                  const int* __restrict__ wsI,
                                                  ushort_t* __restrict__ hidden) {
  int rowbase = blockIdx.y * BM;
  if (rowbase >= wsI[OFF_PADOFF + E_NUM]) return;
  int e = 0;
#pragma unroll
  for (int i = 1; i < E_NUM; i++) e += (rowbase >= wsI[OFF_PADOFF + i]) ? 1 : 0;
  int n0 = blockIdx.x * BN1;

  __shared__ __align__(16) ushort_t As[BM * BK];
  __shared__ __align__(16) ushort_t B1s[BN1 * BK];
  __shared__ __align__(16) ushort_t B3s[BN1 * BK];

  const int tid = threadIdx.x;
  const int lane = tid & 63;
  const int wave = tid >> 6;

  const float* Wsel = (tid < 128) ? (W1 + (size_t)e * C_DIM * H_DIM)
                                  : (W3 + (size_t)e * C_DIM * H_DIM);
  char* Bldssel = (char*)((tid < 128) ? B1s : B3s);
  int tid2 = tid & 127;
  int nb = tid2 & 15;        // 4-col block
  int kb2 = tid2 >> 4;       // 0..7 -> two 4-row blocks each

  int ar = tid >> 1;         // A row 0..127
  int ac4 = (tid & 1) * 4;   // chunk base (16B chunks of 8 bf16)
  const ushort_t* Asrc = packA + (size_t)(rowbase + ar) * C_DIM;

  f32x4 acc1[4][2], acc3[4][2];
  const f32x4 fz = {0.f, 0.f, 0.f, 0.f};
#pragma unroll
  for (int mr = 0; mr < 4; mr++)
#pragma unroll
    for (int nr = 0; nr < 2; nr++) { acc1[mr][nr] = fz; acc3[mr][nr] = fz; }

  const int row0 = (wave >> 1) * 64;   // wave tile: 64 rows x 32 cols (per matrix)
  const int col0 = (wave & 1) * 32;

  for (int k0 = 0; k0 < C_DIM; k0 += BK) {
    // stage A (bf16, chunk-XOR swizzle)
#pragma unroll
    for (int j = 0; j < 4; j++) {
      int c = ac4 + j;
      s16x8 v = *(const s16x8*)(Asrc + k0 + c * 8);
      *(s16x8*)((char*)As + ar * 128 + ((c ^ (ar & 7)) * 16)) = v;
    }
    // stage B: fp32 4x4 blocks -> transpose -> bf16, store [n][k] swizzled
#pragma unroll
    for (int b = 0; b < 2; b++) {
      int kb = kb2 * 2 + b;
      const float* p = Wsel + (size_t)(k0 + kb * 4) * H_DIM + n0 + nb * 4;
      float4 r0 = *(const float4*)(p);
      float4 r1 = *(const float4*)(p + H_DIM);
      float4 r2 = *(const float4*)(p + 2 * H_DIM);
      float4 r3 = *(const float4*)(p + 3 * H_DIM);
      const float* q0 = (const float*)&r0;
      const float* q1 = (const float*)&r1;
      const float* q2 = (const float*)&r2;
      const float* q3 = (const float*)&r3;
#pragma unroll
      for (int i = 0; i < 4; i++) {
        int n = nb * 4 + i;
        u16x4 ov = { f2bf(q0[i]), f2bf(q1[i]), f2bf(q2[i]), f2bf(q3[i]) };
        *(u16x4*)(Bldssel + n * 128 + (((kb >> 1) ^ (n & 7)) * 16) + (kb & 1) * 8) = ov;
      }
    }
    __syncthreads();
#pragma unroll
    for (int kk = 0; kk < 2; kk++) {
      s16x8 af[4], b1f[2], b3f[2];
      int cg = kk * 4 + (lane >> 4);
#pragma unroll
      for (int mr = 0; mr < 4; mr++) {
        int r = row0 + mr * 16 + (lane & 15);
        af[mr] = *(const s16x8*)((const char*)As + r * 128 + ((cg ^ (r & 7)) * 16));
      }
#pragma unroll
      for (int nr = 0; nr < 2; nr++) {
        int n = col0 + nr * 16 + (lane & 15);
        int off = n * 128 + ((cg ^ (n & 7)) * 16);
        b1f[nr] = *(const s16x8*)((const char*)B1s + off);
        b3f[nr] = *(const s16x8*)((const char*)B3s + off);
      }
#pragma unroll
      for (int mr = 0; mr < 4; mr++)
#pragma unroll
        for (int nr = 0; nr < 2; nr++) {
          mfma_bf16(acc1[mr][nr], af[mr], b1f[nr]);
          mfma_bf16(acc3[mr][nr], af[mr], b3f[nr]);
        }
    }
    __syncthreads();
  }

  asm volatile("s_nop 7\n\ts_nop 7");   // MFMA->VALU read hazard guard
#pragma unroll
  for (int mr = 0; mr < 4; mr++)
#pragma unroll
    for (int nr = 0; nr < 2; nr++) {
      f32x4 v1 = acc1[mr][nr];
      f32x4 v3 = acc3[mr][nr];
#pragma unroll
      for (int g = 0; g < 4; g++) {
        float h1 = v1[g], h3 = v3[g];
        float hv = (h1 / (1.f + __expf(-h1))) * h3;   // silu(h1)*h3
        int r = row0 + mr * 16 + (lane >> 4) * 4 + g;
        int cc = n0 + col0 + nr * 16 + (lane & 15);
        hidden[(size_t)(rowbase + r) * H_DIM + cc] = f2bf(hv);
      }
    }
}

// ---------------- GEMM2: out[tok] += w * (hidden @ W2[e]) ----------------
__global__ __launch_bounds__(256, 2) void gemm2_k(const ushort_t* __restrict__ hidden,
                                                  const float* __restrict__ W2,
                                                  const int* __restrict__ wsI,
                                                  float* __restrict__ out) {
  int rowbase = blockIdx.y * BM;
  if (rowbase >= wsI[OFF_PADOFF + E_NUM]) return;
  int e = 0;
#pragma unroll
  for (int i = 1; i < E_NUM; i++) e += (rowbase >= wsI[OFF_PADOFF + i]) ? 1 : 0;
  int n0 = blockIdx.x * BN2;

  __shared__ __align__(16) ushort_t As[BM * BK];
  __shared__ __align__(16) ushort_t Bs[BN2 * BK];

  const int tid = threadIdx.x;
  const int lane = tid & 63;
  const int wave = tid >> 6;

  const float* W2e = W2 + (size_t)e * H_DIM * C_DIM;
  int nb = tid & 31;       // 4-col block (128 cols)
  int kb2 = tid >> 5;      // 0..7 -> two 4-row blocks each

  int ar = tid >> 1;
  int ac4 = (tid & 1) * 4;
  const ushort_t* Asrc = hidden + (size_t)(rowbase + ar) * H_DIM;

  f32x4 acc[4][4];
  const f32x4 fz = {0.f, 0.f, 0.f, 0.f};
#pragma unroll
  for (int mr = 0; mr < 4; mr++)
#pragma unroll
    for (int nr = 0; nr < 4; nr++) acc[mr][nr] = fz;

  const int row0 = (wave >> 1) * 64;   // wave tile 64x64
  const int col0 = (wave & 1) * 64;

  for (int k0 = 0; k0 < H_DIM; k0 += BK) {
#pragma unroll
    for (int j = 0; j < 4; j++) {
      int c = ac4 + j;
      s16x8 v = *(const s16x8*)(Asrc + k0 + c * 8);
      *(s16x8*)((char*)As + ar * 128 + ((c ^ (ar & 7)) * 16)) = v;
    }
#pragma unroll
    for (int b = 0; b < 2; b++) {
      int kb = kb2 * 2 + b;
      const float* p = W2e + (size_t)(k0 + kb * 4) * C_DIM + n0 + nb * 4;
      float4 r0 = *(const float4*)(p);
      float4 r1 = *(const float4*)(p + C_DIM);
      float4 r2 = *(const float4*)(p + 2 * C_DIM);
      float4 r3 = *(const float4*)(p + 3 * C_DIM);
      const float* q0 = (const float*)&r0;
      const float* q1 = (const float*)&r1;
      const float* q2 = (const float*)&r2;
      const float* q3 = (const float*)&r3;
#pragma unroll
      for (int i = 0; i < 4; i++) {
        int n = nb * 4 + i;
        u16x4 ov = { f2bf(q0[i]), f2bf(q1[i]), f2bf(q2[i]), f2bf(q3[i]) };
        *(u16x4*)((char*)Bs + n * 128 + (((kb >> 1) ^ (n & 7)) * 16) + (kb & 1) * 8) = ov;
      }
    }
    __syncthreads();
#pragma unroll
    for (int kk = 0; kk < 2; kk++) {
      s16x8 af[4], bf[4];
      int cg = kk * 4 + (lane >> 4);
#pragma unroll
      for (int mr = 0; mr < 4; mr++) {
        int r = row0 + mr * 16 + (lane & 15);
        af[mr] = *(const s16x8*)((const char*)As + r * 128 + ((cg ^ (r & 7)) * 16));
      }
#pragma unroll
      for (int nr = 0; nr < 4; nr++) {
        int n = col0 + nr * 16 + (lane & 15);
        bf[nr] = *(const s16x8*)((const char*)Bs + n * 128 + ((cg ^ (n & 7)) * 16));
      }
#pragma unroll
      for (int mr = 0; mr < 4; mr++)
#pragma unroll
        for (int nr = 0; nr < 4; nr++) mfma_bf16(acc[mr][nr], af[mr], bf[nr]);
    }
    __syncthreads();
  }

  asm volatile("s_nop 7\n\ts_nop 7");
  const int* atok = wsI + OFF_ATOK;
  const float* aw = (const float*)(wsI + OFF_AW);
#pragma unroll
  for (int mr = 0; mr < 4; mr++)
#pragma unroll
    for (int g = 0; g < 4; g++) {
      int r = rowbase + row0 + mr * 16 + (lane >> 4) * 4 + g;
      int t = atok[r];
      float w = aw[r];
      if (w != 0.f) {
#pragma unroll
        for (int nr = 0; nr < 4; nr++) {
          atomicAdd(&out[(size_t)t * C_DIM + n0 + col0 + nr * 16 + (lane & 15)],
                    w * acc[mr][nr][g]);
        }
      }
    }
}

extern "C" void kernel_launch(void* const* d_in, const int* in_sizes, int n_in,
                              void* d_out, int out_size, void* d_ws, size_t ws_size,
                              hipStream_t stream) {
  (void)in_sizes; (void)n_in; (void)ws_size;
  const float* x  = (const float*)d_in[0];
  const float* Wg = (const float*)d_in[1];
  const float* W1 = (const float*)d_in[2];
  const float* W3 = (const float*)d_in[3];
  const float* W2 = (const float*)d_in[4];
  float* out = (float*)d_out;
  char* ws = (char*)d_ws;
  int* wsI = (int*)ws;
  ushort_t* packA  = (ushort_t*)(ws + BOFF_PACKA);
  ushort_t* hidden = (ushort_t*)(ws + BOFF_HIDDEN);

  hipMemsetAsync(ws, 0, 256, stream);                               // counts/fill
  hipMemsetAsync(d_out, 0, sizeof(float) * (size_t)out_size, stream);
  router_k<<<N_TOK / 4, 256, 0, stream>>>(x, Wg, wsI);
  offsets_k<<<1, 256, 0, stream>>>(wsI);
  scatter_k<<<N_TOK * 2 / 256, 256, 0, stream>>>(wsI);
  pack_k<<<MAXROWS / 2, 256, 0, stream>>>(x, wsI, packA);
  gemm1_k<<<dim3(H_DIM / BN1, MAXTILES, 1), 256, 0, stream>>>(packA, W1, W3, wsI, hidden);
  gemm2_k<<<dim3(C_DIM / BN2, MAXTILES, 1), 256, 0, stream>>>(hidden, W2, wsI, out);
}

// Round 2
// 802.737 us; speedup vs baseline: 1.2326x; 1.2326x over previous
//
#include <hip/hip_runtime.h>
#include <stdint.h>

// MoE FFN: B=4 T=1024 C=1024 H=4096 E=8 K=2 (N=4096 tokens, 8192 assignments)
// Sparse top-2, bf16 MFMA fp32-accum, bf16 weight pre-pass (transposed),
// global_load_lds staging with pre-swizzled sources, no atomics.
// ws need: ~296 MB.

#define N_TOK 4096
#define C_DIM 1024
#define H_DIM 4096
#define E_NUM 8
#define BM 128
#define BK 64
#define MAXROWS 9216
#define MAXTILES 72

typedef float f32x4 __attribute__((ext_vector_type(4)));
typedef short s16x8 __attribute__((ext_vector_type(8)));
typedef unsigned short u16x4 __attribute__((ext_vector_type(4)));
typedef unsigned short ushort_t;

// ---- ws header (int indices) ----
#define OFF_COUNTS 0
#define OFF_FILL   8
#define OFF_PADOFF 16
#define OFF_TOKIDX 64
#define OFF_TOKW   (OFF_TOKIDX + N_TOK * 2)   // float[8192]
#define OFF_ATOK   (OFF_TOKW + N_TOK * 2)     // int[MAXROWS]
#define OFF_POSOF  (OFF_ATOK + MAXROWS)       // int[8192]
// ---- ws big buffers (byte offsets, 256-aligned) ----
#define BOFF_PACKA  ((size_t)135680)                              // bf16 [MAXROWS][C]
#define BOFF_HIDDEN (BOFF_PACKA + (size_t)MAXROWS * C_DIM * 2)    // bf16 [MAXROWS][H]
#define BOFF_W1T    (BOFF_HIDDEN + (size_t)MAXROWS * H_DIM * 2)   // bf16 [E][H][C]
#define BOFF_W3T    (BOFF_W1T + (size_t)E_NUM * H_DIM * C_DIM * 2)
#define BOFF_W2T    (BOFF_W3T + (size_t)E_NUM * H_DIM * C_DIM * 2) // bf16 [E][C][H]
#define BOFF_EXPOUT BOFF_W1T  // fp32 [MAXROWS][C]; W1T dead once gemm2 runs

__device__ __forceinline__ ushort_t f2bf(float f) {
  uint32_t u = __float_as_uint(f);
  u += 0x7FFFu + ((u >> 16) & 1u);   // RNE
  return (ushort_t)(u >> 16);
}

__device__ __forceinline__ void mfma_bf16(f32x4& d, s16x8 a, s16x8 b) {
  asm volatile("v_mfma_f32_16x16x32_bf16 %0, %1, %2, %0" : "+v"(d) : "v"(a), "v"(b));
}

__device__ __forceinline__ void gload_lds16(const void* g, void* l) {
  __builtin_amdgcn_global_load_lds((const __attribute__((address_space(1))) void*)g,
                                   (__attribute__((address_space(3))) void*)l, 16, 0, 0);
}

// ---------------- router ----------------
__global__ __launch_bounds__(256) void router_k(const float* __restrict__ x,
                                                const float* __restrict__ Wg,
                                                int* __restrict__ wsI) {
  int lane = threadIdx.x & 63;
  int wave = threadIdx.x >> 6;
  int t = blockIdx.x * 4 + wave;
  const float* xr = x + (size_t)t * C_DIM;
  float acc[E_NUM];
#pragma unroll
  for (int e = 0; e < E_NUM; e++) acc[e] = 0.f;
#pragma unroll
  for (int i = 0; i < C_DIM / 64; i++) {
    int c = i * 64 + lane;
    float xv = xr[c];
    const float4* wr = (const float4*)(Wg + (size_t)c * E_NUM);
    float4 w0 = wr[0], w1 = wr[1];
    acc[0] += xv * w0.x; acc[1] += xv * w0.y;
    acc[2] += xv * w0.z; acc[3] += xv * w0.w;
    acc[4] += xv * w1.x; acc[5] += xv * w1.y;
    acc[6] += xv * w1.z; acc[7] += xv * w1.w;
  }
#pragma unroll
  for (int e = 0; e < E_NUM; e++) {
    float v = acc[e];
#pragma unroll
    for (int off = 32; off > 0; off >>= 1) v += __shfl_down(v, off);
    acc[e] = v;
  }
  if (lane == 0) {
    float m0 = -1e30f, m1 = -1e30f;
    int i0 = 0, i1 = 0;
#pragma unroll
    for (int e = 0; e < E_NUM; e++) {
      float v = acc[e];
      if (v > m0) { m1 = m0; i1 = i0; m0 = v; i0 = e; }
      else if (v > m1) { m1 = v; i1 = e; }
    }
    float w0 = 1.f / (1.f + __expf(m1 - m0));   // renorm top-2; softmax denom cancels
    wsI[OFF_TOKIDX + t * 2] = i0;
    wsI[OFF_TOKIDX + t * 2 + 1] = i1;
    float* tw = (float*)(wsI + OFF_TOKW);
    tw[t * 2] = w0;
    tw[t * 2 + 1] = 1.f - w0;
    atomicAdd(&wsI[OFF_COUNTS + i0], 1);
    atomicAdd(&wsI[OFF_COUNTS + i1], 1);
  }
}

// ---------------- offsets ----------------
__global__ __launch_bounds__(256) void offsets_k(int* __restrict__ wsI) {
  __shared__ int s_off[E_NUM], s_cnt[E_NUM], s_pad[E_NUM];
  if (threadIdx.x == 0) {
    int tot = 0;
    for (int e = 0; e < E_NUM; e++) {
      int c = wsI[OFF_COUNTS + e];
      s_cnt[e] = c;
      s_off[e] = tot;
      int p = (c + BM - 1) / BM * BM;
      s_pad[e] = p;
      tot += p;
      wsI[OFF_PADOFF + e] = s_off[e];
    }
    wsI[OFF_PADOFF + E_NUM] = tot;
  }
  __syncthreads();
  int* atok = wsI + OFF_ATOK;
  for (int e = 0; e < E_NUM; e++) {
    int start = s_off[e] + s_cnt[e];
    int end = s_off[e] + s_pad[e];
    for (int r = start + (int)threadIdx.x; r < end; r += 256) atok[r] = 0; // pad row
  }
}

// ---------------- scatter ----------------
__global__ __launch_bounds__(256) void scatter_k(int* __restrict__ wsI) {
  int g = blockIdx.x * 256 + threadIdx.x;   // token*2+k
  int e = wsI[OFF_TOKIDX + g];
  int pos = wsI[OFF_PADOFF + e] + atomicAdd(&wsI[OFF_FILL + e], 1);
  wsI[OFF_ATOK + pos] = g >> 1;
  wsI[OFF_POSOF + g] = pos;
}

// ---------------- pack x rows -> bf16 ----------------
__global__ __launch_bounds__(256) void pack_k(const float* __restrict__ x,
                                              const int* __restrict__ wsI,
                                              ushort_t* __restrict__ packA) {
  int row = blockIdx.x * 2 + (threadIdx.x >> 7);
  if (row >= wsI[OFF_PADOFF + E_NUM]) return;
  int t = wsI[OFF_ATOK + row];
  int c = (threadIdx.x & 127) * 8;
  const float4* src = (const float4*)(x + (size_t)t * C_DIM + c);
  float4 a = src[0], b = src[1];
  u16x4 o0 = { f2bf(a.x), f2bf(a.y), f2bf(a.z), f2bf(a.w) };
  u16x4 o1 = { f2bf(b.x), f2bf(b.y), f2bf(b.z), f2bf(b.w) };
  *(u16x4*)(packA + (size_t)row * C_DIM + c) = o0;
  *(u16x4*)(packA + (size_t)row * C_DIM + c + 4) = o1;
}

// ---------------- transpose+cvt: src fp32 [R][Cd] -> dst bf16 [Cd][R], per expert z ----------------
__global__ __launch_bounds__(256) void tcvt_k(const float* __restrict__ src,
                                              ushort_t* __restrict__ dst,
                                              int R, int Cd) {
  size_t esz = (size_t)R * Cd;
  const float* s = src + (size_t)blockIdx.z * esz;
  ushort_t* d = dst + (size_t)blockIdx.z * esz;
  int r0 = blockIdx.y * 64, c0 = blockIdx.x * 64;
  __shared__ ushort_t tileT[64][72];   // [c][r], 144B stride (16B aligned)
  int tr = threadIdx.x >> 4;           // 0..15
  int tc = threadIdx.x & 15;           // 0..15
#pragma unroll
  for (int j = 0; j < 4; j++) {
    int r = tr + j * 16;
    float4 v = *(const float4*)(s + (size_t)(r0 + r) * Cd + c0 + tc * 4);
    tileT[tc * 4 + 0][r] = f2bf(v.x);
    tileT[tc * 4 + 1][r] = f2bf(v.y);
    tileT[tc * 4 + 2][r] = f2bf(v.z);
    tileT[tc * 4 + 3][r] = f2bf(v.w);
  }
  __syncthreads();
  int cr = threadIdx.x >> 3;           // 0..31
  int ch = threadIdx.x & 7;
#pragma unroll
  for (int jj = 0; jj < 2; jj++) {
    int cc = jj * 32 + cr;
    s16x8 v = *(const s16x8*)&tileT[cc][ch * 8];
    *(s16x8*)(d + (size_t)(c0 + cc) * R + r0 + ch * 8) = v;
  }
}

// ---------------- GEMM1: hidden = silu(A@W1t^T)*(A@W3t^T) ----------------
// A: packA [M][C] bf16 ; W1t/W3t: [E][H][C] bf16 (n-major, k-contiguous)
__global__ __launch_bounds__(256, 2) void gemm1_k(const ushort_t* __restrict__ packA,
                                                  const ushort_t* __restrict__ W1T,
                                                  const ushort_t* __restrict__ W3T,
                                                  const int* __restrict__ wsI,
                                                  ushort_t* __restrict__ hidden) {
  int rowbase = blockIdx.y * BM;
  if (rowbase >= wsI[OFF_PADOFF + E_NUM]) return;
  int e = 0;
#pragma unroll
  for (int i = 1; i < E_NUM; i++) e += (rowbase >= wsI[OFF_PADOFF + i]) ? 1 : 0;
  int n0 = blockIdx.x * 64;
  const ushort_t* w1e = W1T + (size_t)e * H_DIM * C_DIM;
  const ushort_t* w3e = W3T + (size_t)e * H_DIM * C_DIM;

  // LDS 32KB linear: A [0,16K) 128 rows x 128B ; B1 [16K,24K) ; B3 [24K,32K) 64 rows x 128B
  __shared__ __align__(16) ushort_t lds[16384];
  char* ldsc = (char*)lds;

  const int tid = threadIdx.x, lane = tid & 63, wave = tid >> 6;
  const int row0 = (wave >> 1) * 64, col0 = (wave & 1) * 32;

  // per-issue pre-swizzled global bases (linear LDS dest, src chunk c^(row&7))
  const ushort_t* bases[8];
#pragma unroll
  for (int i = 0; i < 8; i++) {
    int seg = (wave * 8 + i) << 10;
    int lin = seg + (lane << 4);
    if (seg < 16384) {
      int r = lin >> 7, c = (lin >> 4) & 7;
      bases[i] = packA + (size_t)(rowbase + r) * C_DIM + ((c ^ (r & 7)) << 3);
    } else if (seg < 24576) {
      int o = lin - 16384; int n = o >> 7, c = (o >> 4) & 7;
      bases[i] = w1e + (size_t)(n0 + n) * C_DIM + ((c ^ (n & 7)) << 3);
    } else {
      int o = lin - 24576; int n = o >> 7, c = (o >> 4) & 7;
      bases[i] = w3e + (size_t)(n0 + n) * C_DIM + ((c ^ (n & 7)) << 3);
    }
  }

  f32x4 acc1[4][2], acc3[4][2];
  const f32x4 fz = {0.f, 0.f, 0.f, 0.f};
#pragma unroll
  for (int mr = 0; mr < 4; mr++)
#pragma unroll
    for (int nr = 0; nr < 2; nr++) { acc1[mr][nr] = fz; acc3[mr][nr] = fz; }

  for (int k0 = 0; k0 < C_DIM; k0 += BK) {
#pragma unroll
    for (int i = 0; i < 8; i++)
      gload_lds16(bases[i] + k0, ldsc + ((wave * 8 + i) << 10));
    __syncthreads();
#pragma unroll
    for (int kk = 0; kk < 2; kk++) {
      int cg = kk * 4 + (lane >> 4);
      s16x8 af[4], b1f[2], b3f[2];
#pragma unroll
      for (int mr = 0; mr < 4; mr++) {
        int r = row0 + mr * 16 + (lane & 15);
        af[mr] = *(const s16x8*)(ldsc + r * 128 + ((cg ^ (r & 7)) << 4));
      }
#pragma unroll
      for (int nr = 0; nr < 2; nr++) {
        int n = col0 + nr * 16 + (lane & 15);
        int o = n * 128 + ((cg ^ (n & 7)) << 4);
        b1f[nr] = *(const s16x8*)(ldsc + 16384 + o);
        b3f[nr] = *(const s16x8*)(ldsc + 24576 + o);
      }
#pragma unroll
      for (int mr = 0; mr < 4; mr++)
#pragma unroll
        for (int nr = 0; nr < 2; nr++) {
          mfma_bf16(acc1[mr][nr], af[mr], b1f[nr]);
          mfma_bf16(acc3[mr][nr], af[mr], b3f[nr]);
        }
    }
    __syncthreads();
  }

  asm volatile("s_nop 7\n\ts_nop 7");
#pragma unroll
  for (int mr = 0; mr < 4; mr++)
#pragma unroll
    for (int nr = 0; nr < 2; nr++) {
#pragma unroll
      for (int g = 0; g < 4; g++) {
        float h1 = acc1[mr][nr][g], h3 = acc3[mr][nr][g];
        float hv = (h1 / (1.f + __expf(-h1))) * h3;
        int r = row0 + mr * 16 + (lane >> 4) * 4 + g;
        int cc = n0 + col0 + nr * 16 + (lane & 15);
        hidden[(size_t)(rowbase + r) * H_DIM + cc] = f2bf(hv);
      }
    }
}

// ---------------- GEMM2: expOut = hidden @ W2t^T (per-assignment rows, no atomics) ----------------
// A: hidden [M][H] bf16 ; W2t: [E][C][H] bf16
__global__ __launch_bounds__(256, 2) void gemm2_k(const ushort_t* __restrict__ hidden,
                                                  const ushort_t* __restrict__ W2T,
                                                  const int* __restrict__ wsI,
                                                  float* __restrict__ expOut) {
  int rowbase = blockIdx.y * BM;
  if (rowbase >= wsI[OFF_PADOFF + E_NUM]) return;
  int e = 0;
#pragma unroll
  for (int i = 1; i < E_NUM; i++) e += (rowbase >= wsI[OFF_PADOFF + i]) ? 1 : 0;
  int n0 = blockIdx.x * 128;
  const ushort_t* w2e = W2T + (size_t)e * C_DIM * H_DIM;

  // LDS 32KB: A [0,16K) 128 rows x 128B ; B [16K,32K) 128 rows x 128B
  __shared__ __align__(16) ushort_t lds[16384];
  char* ldsc = (char*)lds;

  const int tid = threadIdx.x, lane = tid & 63, wave = tid >> 6;
  const int row0 = (wave >> 1) * 64, col0 = (wave & 1) * 64;

  const ushort_t* bases[8];
#pragma unroll
  for (int i = 0; i < 8; i++) {
    int seg = (wave * 8 + i) << 10;
    int lin = seg + (lane << 4);
    if (seg < 16384) {
      int r = lin >> 7, c = (lin >> 4) & 7;
      bases[i] = hidden + (size_t)(rowbase + r) * H_DIM + ((c ^ (r & 7)) << 3);
    } else {
      int o = lin - 16384; int n = o >> 7, c = (o >> 4) & 7;
      bases[i] = w2e + (size_t)(n0 + n) * H_DIM + ((c ^ (n & 7)) << 3);
    }
  }

  f32x4 acc[4][4];
  const f32x4 fz = {0.f, 0.f, 0.f, 0.f};
#pragma unroll
  for (int mr = 0; mr < 4; mr++)
#pragma unroll
    for (int nr = 0; nr < 4; nr++) acc[mr][nr] = fz;

  for (int k0 = 0; k0 < H_DIM; k0 += BK) {
#pragma unroll
    for (int i = 0; i < 8; i++)
      gload_lds16(bases[i] + k0, ldsc + ((wave * 8 + i) << 10));
    __syncthreads();
#pragma unroll
    for (int kk = 0; kk < 2; kk++) {
      int cg = kk * 4 + (lane >> 4);
      s16x8 af[4], bf[4];
#pragma unroll
      for (int mr = 0; mr < 4; mr++) {
        int r = row0 + mr * 16 + (lane & 15);
        af[mr] = *(const s16x8*)(ldsc + r * 128 + ((cg ^ (r & 7)) << 4));
      }
#pragma unroll
      for (int nr = 0; nr < 4; nr++) {
        int n = col0 + nr * 16 + (lane & 15);
        bf[nr] = *(const s16x8*)(ldsc + 16384 + n * 128 + ((cg ^ (n & 7)) << 4));
      }
#pragma unroll
      for (int mr = 0; mr < 4; mr++)
#pragma unroll
        for (int nr = 0; nr < 4; nr++) mfma_bf16(acc[mr][nr], af[mr], bf[nr]);
    }
    __syncthreads();
  }

  asm volatile("s_nop 7\n\ts_nop 7");
#pragma unroll
  for (int mr = 0; mr < 4; mr++)
#pragma unroll
    for (int g = 0; g < 4; g++) {
      int r = rowbase + row0 + mr * 16 + (lane >> 4) * 4 + g;
#pragma unroll
      for (int nr = 0; nr < 4; nr++)
        expOut[(size_t)r * C_DIM + n0 + col0 + nr * 16 + (lane & 15)] = acc[mr][nr][g];
    }
}

// ---------------- combine: out[t] = w0*expOut[p0] + w1*expOut[p1] ----------------
__global__ __launch_bounds__(256) void combine_k(const float* __restrict__ expOut,
                                                 const int* __restrict__ wsI,
                                                 float* __restrict__ out) {
  int t = blockIdx.x;
  int c = threadIdx.x * 4;
  const float* tw = (const float*)(wsI + OFF_TOKW);
  int p0 = wsI[OFF_POSOF + t * 2], p1 = wsI[OFF_POSOF + t * 2 + 1];
  float w0 = tw[t * 2], w1 = tw[t * 2 + 1];
  float4 a = *(const float4*)(expOut + (size_t)p0 * C_DIM + c);
  float4 b = *(const float4*)(expOut + (size_t)p1 * C_DIM + c);
  float4 o;
  o.x = w0 * a.x + w1 * b.x;
  o.y = w0 * a.y + w1 * b.y;
  o.z = w0 * a.z + w1 * b.z;
  o.w = w0 * a.w + w1 * b.w;
  *(float4*)(out + (size_t)t * C_DIM + c) = o;
}

extern "C" void kernel_launch(void* const* d_in, const int* in_sizes, int n_in,
                              void* d_out, int out_size, void* d_ws, size_t ws_size,
                              hipStream_t stream) {
  (void)in_sizes; (void)n_in; (void)out_size; (void)ws_size;
  const float* x  = (const float*)d_in[0];
  const float* Wg = (const float*)d_in[1];
  const float* W1 = (const float*)d_in[2];
  const float* W3 = (const float*)d_in[3];
  const float* W2 = (const float*)d_in[4];
  float* out = (float*)d_out;
  char* ws = (char*)d_ws;
  int* wsI = (int*)ws;
  ushort_t* packA  = (ushort_t*)(ws + BOFF_PACKA);
  ushort_t* hidden = (ushort_t*)(ws + BOFF_HIDDEN);
  ushort_t* W1Tp   = (ushort_t*)(ws + BOFF_W1T);
  ushort_t* W3Tp   = (ushort_t*)(ws + BOFF_W3T);
  ushort_t* W2Tp   = (ushort_t*)(ws + BOFF_W2T);
  float*    expOut = (float*)(ws + BOFF_EXPOUT);

  hipMemsetAsync(ws, 0, 256, stream);   // counts/fill
  router_k<<<N_TOK / 4, 256, 0, stream>>>(x, Wg, wsI);
  offsets_k<<<1, 256, 0, stream>>>(wsI);
  scatter_k<<<N_TOK * 2 / 256, 256, 0, stream>>>(wsI);
  // weight cvt+transpose: W1/W3 [C][H]->[H][C], W2 [H][C]->[C][H]
  tcvt_k<<<dim3(H_DIM / 64, C_DIM / 64, E_NUM), 256, 0, stream>>>(W1, W1Tp, C_DIM, H_DIM);
  tcvt_k<<<dim3(H_DIM / 64, C_DIM / 64, E_NUM), 256, 0, stream>>>(W3, W3Tp, C_DIM, H_DIM);
  tcvt_k<<<dim3(C_DIM / 64, H_DIM / 64, E_NUM), 256, 0, stream>>>(W2, W2Tp, H_DIM, C_DIM);
  pack_k<<<MAXROWS / 2, 256, 0, stream>>>(x, wsI, packA);
  gemm1_k<<<dim3(H_DIM / 64, MAXTILES), 256, 0, stream>>>(packA, W1Tp, W3Tp, wsI, hidden);
  gemm2_k<<<dim3(C_DIM / 128, MAXTILES), 256, 0, stream>>>(hidden, W2Tp, wsI, expOut);
  combine_k<<<N_TOK, 256, 0, stream>>>(expOut, wsI, out);
}